// Round 1
// baseline (662.142 us; speedup 1.0000x reference)
//
#include <hip/hip_runtime.h>
#include <stdint.h>

#define AS1 __attribute__((address_space(1)))
#define AS3 __attribute__((address_space(3)))

typedef __attribute__((ext_vector_type(8))) __bf16 bf16x8;
typedef __attribute__((ext_vector_type(4))) float f32x4;

__device__ __forceinline__ unsigned short f2bf(float f) {
  unsigned int u = __float_as_uint(f);
  u = (u + 0x7FFFu + ((u >> 16) & 1u)) >> 16;
  return (unsigned short)u;
}

// blended[g] = sum_p routing[p] * ps[p*G+g]
__global__ void blend_k(const float* __restrict__ ps, const float* __restrict__ rt,
                        float* __restrict__ blended, int G, int P) {
  int g = blockIdx.x * blockDim.x + threadIdx.x;
  if (g >= G) return;
  float s = 0.f;
  for (int p = 0; p < P; ++p) s += rt[p] * ps[(size_t)p * G + g];
  blended[g] = s;
}

// w_bf16[i] = bf16(signs[i] * blended[i/128]); 4 elems per thread.
// flat index i = n*K + k; group = i/128 exactly (K=4096 divisible by 128).
__global__ void build_w_k(const float4* __restrict__ signs, const float* __restrict__ blended,
                          ushort4* __restrict__ w, int n4) {
  int t = blockIdx.x * blockDim.x + threadIdx.x;
  if (t >= n4) return;
  float4 s = signs[t];
  float sc = blended[t >> 5];  // (t*4) >> 7
  ushort4 o;
  o.x = f2bf(s.x * sc); o.y = f2bf(s.y * sc);
  o.z = f2bf(s.z * sc); o.w = f2bf(s.w * sc);
  w[t] = o;
}

__global__ void cvt_x_k(const float4* __restrict__ x, ushort4* __restrict__ xb, int n4) {
  int t = blockIdx.x * blockDim.x + threadIdx.x;
  if (t >= n4) return;
  float4 s = x[t];
  ushort4 o;
  o.x = f2bf(s.x); o.y = f2bf(s.y); o.z = f2bf(s.z); o.w = f2bf(s.w);
  xb[t] = o;
}

// C[M,N] = A[M,K] * B[N,K]^T, all bf16 inputs, fp32 out. 128x128 tile, BK=64,
// 256 threads = 4 waves in 2x2, each wave 64x64 via 4x4 of 16x16x32 MFMA.
#define BM 128
#define BN 128
#define BK 64

__global__ __launch_bounds__(256) void gemm_bt_k(
    const unsigned short* __restrict__ A, const unsigned short* __restrict__ B,
    float* __restrict__ C, int M, int N, int K) {
  __shared__ __align__(16) unsigned short sA[BM * BK];
  __shared__ __align__(16) unsigned short sB[BN * BK];
  const int tid  = threadIdx.x;
  const int lane = tid & 63;
  const int wave = tid >> 6;
  const int bm = blockIdx.y * BM;
  const int bn = blockIdx.x * BN;
  const int wm = (wave >> 1) * 64;
  const int wn = (wave & 1) * 64;

  f32x4 acc[4][4];
#pragma unroll
  for (int i = 0; i < 4; ++i)
#pragma unroll
    for (int j = 0; j < 4; ++j) acc[i][j] = (f32x4){0.f, 0.f, 0.f, 0.f};

  const int srow = lane >> 3;       // 0..7 within 8-row chunk
  const int scol = (lane & 7) * 8;  // bf16 elements, 16B per lane
  const int fr = lane & 15;
  const int fq = lane >> 4;

  for (int k0 = 0; k0 < K; k0 += BK) {
    // stage A,B tiles: chunk c covers rows [c*8, c*8+8), 64 lanes x 16B = 1KB
#pragma unroll
    for (int i = 0; i < 4; ++i) {
      const int c = wave * 4 + i;
      const int row = c * 8 + srow;
      __builtin_amdgcn_global_load_lds(
          (AS1 unsigned int*)(A + (size_t)(bm + row) * K + k0 + scol),
          (AS3 unsigned int*)(sA + c * 512), 16, 0, 0);
      __builtin_amdgcn_global_load_lds(
          (AS1 unsigned int*)(B + (size_t)(bn + row) * K + k0 + scol),
          (AS3 unsigned int*)(sB + c * 512), 16, 0, 0);
    }
    __syncthreads();
#pragma unroll
    for (int ks = 0; ks < 2; ++ks) {
      bf16x8 af[4], bfr[4];
#pragma unroll
      for (int mi = 0; mi < 4; ++mi)
        af[mi] = *(const bf16x8*)(sA + (wm + mi * 16 + fr) * BK + ks * 32 + fq * 8);
#pragma unroll
      for (int ni = 0; ni < 4; ++ni)
        bfr[ni] = *(const bf16x8*)(sB + (wn + ni * 16 + fr) * BK + ks * 32 + fq * 8);
#pragma unroll
      for (int mi = 0; mi < 4; ++mi)
#pragma unroll
        for (int ni = 0; ni < 4; ++ni)
          acc[mi][ni] = __builtin_amdgcn_mfma_f32_16x16x32_bf16(af[mi], bfr[ni], acc[mi][ni], 0, 0, 0);
    }
    __syncthreads();
  }

  // C/D layout: col = lane&15, row = (lane>>4)*4 + reg
#pragma unroll
  for (int mi = 0; mi < 4; ++mi) {
#pragma unroll
    for (int ni = 0; ni < 4; ++ni) {
      const int row0 = bm + wm + mi * 16 + fq * 4;
      const int col  = bn + wn + ni * 16 + fr;
#pragma unroll
      for (int r = 0; r < 4; ++r)
        C[(size_t)(row0 + r) * N + col] = acc[mi][ni][r];
    }
  }
}

// Safety-net exact fp32 kernel (only if ws_size too small) — slow but correct.
__global__ void naive_k(const float* __restrict__ x, const float* __restrict__ signs,
                        const float* __restrict__ ps, const float* __restrict__ rt,
                        float* __restrict__ out, int M, int N, int K, int P) {
  int idx = blockIdx.x * blockDim.x + threadIdx.x;
  if (idx >= M * N) return;
  int m = idx / N, n = idx % N;
  const float* xr = x + (size_t)m * K;
  const float* wr = signs + (size_t)n * K;
  const int NG = K / 128;
  const size_t G = (size_t)N * NG;
  float acc = 0.f;
  for (int g = 0; g < NG; ++g) {
    float sc = 0.f;
    int gi = n * NG + g;
    for (int p = 0; p < P; ++p) sc += rt[p] * ps[(size_t)p * G + gi];
    float s2 = 0.f;
    for (int kk = 0; kk < 128; ++kk) s2 += xr[g * 128 + kk] * wr[g * 128 + kk];
    acc += sc * s2;
  }
  out[idx] = acc;
}

extern "C" void kernel_launch(void* const* d_in, const int* in_sizes, int n_in,
                              void* d_out, int out_size, void* d_ws, size_t ws_size,
                              hipStream_t stream) {
  const float* x     = (const float*)d_in[0];
  const float* signs = (const float*)d_in[1];
  const float* ps    = (const float*)d_in[2];
  const float* rt    = (const float*)d_in[3];
  float* out = (float*)d_out;

  const int K = 4096, N = 4096, GS = 128;
  const int M = in_sizes[0] / K;   // 8192
  const int G = N / GS * K;        // 131072 groups (contiguous in flat [N*K])
  const int P = in_sizes[3];       // 8

  const size_t xb_bytes = (size_t)M * K * 2;
  const size_t wb_bytes = (size_t)N * K * 2;
  const size_t bl_bytes = (size_t)G * 4;
  const size_t need = xb_bytes + wb_bytes + bl_bytes;

  if (ws_size >= need) {
    unsigned short* xb = (unsigned short*)d_ws;
    unsigned short* wb = (unsigned short*)((char*)d_ws + xb_bytes);
    float* blended     = (float*)((char*)d_ws + xb_bytes + wb_bytes);

    blend_k<<<(G + 255) / 256, 256, 0, stream>>>(ps, rt, blended, G, P);

    const int n4w = N * K / 4;
    build_w_k<<<(n4w + 255) / 256, 256, 0, stream>>>(
        (const float4*)signs, blended, (ushort4*)wb, n4w);

    const int n4x = M * K / 4;
    cvt_x_k<<<(n4x + 255) / 256, 256, 0, stream>>>(
        (const float4*)x, (ushort4*)xb, n4x);

    dim3 grid(N / BN, M / BM);
    gemm_bt_k<<<grid, 256, 0, stream>>>(xb, wb, out, M, N, K);
  } else {
    const size_t total = (size_t)M * N;
    naive_k<<<(int)((total + 255) / 256), 256, 0, stream>>>(
        x, signs, ps, rt, out, M, N, K, P);
  }
}

// Round 2
// 597.694 us; speedup vs baseline: 1.1078x; 1.1078x over previous
//
#include <hip/hip_runtime.h>
#include <stdint.h>

#define AS1 __attribute__((address_space(1)))
#define AS3 __attribute__((address_space(3)))

typedef __attribute__((ext_vector_type(8))) __bf16 bf16x8;
typedef __attribute__((ext_vector_type(4))) float f32x4;

__device__ __forceinline__ unsigned short f2bf(float f) {
  unsigned int u = __float_as_uint(f);
  u = (u + 0x7FFFu + ((u >> 16) & 1u)) >> 16;
  return (unsigned short)u;
}

// blended[g] = sum_p routing[p] * ps[p*G+g]
__global__ void blend_k(const float* __restrict__ ps, const float* __restrict__ rt,
                        float* __restrict__ blended, int G, int P) {
  int g = blockIdx.x * blockDim.x + threadIdx.x;
  if (g >= G) return;
  float s = 0.f;
  for (int p = 0; p < P; ++p) s += rt[p] * ps[(size_t)p * G + g];
  blended[g] = s;
}

// 8 elems/thread: w_bf16[i] = bf16(signs[i] * blended[i/128]); 16B stores.
__global__ void build_w_k(const float4* __restrict__ signs, const float* __restrict__ blended,
                          ushort4* __restrict__ w, int n8) {
  int t = blockIdx.x * blockDim.x + threadIdx.x;
  if (t >= n8) return;
  float sc = blended[t >> 4];  // (t*8) >> 7
  float4 s0 = signs[t * 2], s1 = signs[t * 2 + 1];
  ushort4 o0, o1;
  o0.x = f2bf(s0.x * sc); o0.y = f2bf(s0.y * sc);
  o0.z = f2bf(s0.z * sc); o0.w = f2bf(s0.w * sc);
  o1.x = f2bf(s1.x * sc); o1.y = f2bf(s1.y * sc);
  o1.z = f2bf(s1.z * sc); o1.w = f2bf(s1.w * sc);
  w[t * 2] = o0; w[t * 2 + 1] = o1;
}

__global__ void cvt_x_k(const float4* __restrict__ x, ushort4* __restrict__ xb, int n8) {
  int t = blockIdx.x * blockDim.x + threadIdx.x;
  if (t >= n8) return;
  float4 s0 = x[t * 2], s1 = x[t * 2 + 1];
  ushort4 o0, o1;
  o0.x = f2bf(s0.x); o0.y = f2bf(s0.y); o0.z = f2bf(s0.z); o0.w = f2bf(s0.w);
  o1.x = f2bf(s1.x); o1.y = f2bf(s1.y); o1.z = f2bf(s1.z); o1.w = f2bf(s1.w);
  xb[t * 2] = o0; xb[t * 2 + 1] = o1;
}

// C[M,N] = A[M,K] * B[N,K]^T, bf16 in, fp32 out. 128x128 tile, BK=64,
// 4 waves 2x2, each wave 64x64 via 4x4 of 16x16x32 MFMA.
// LDS layout XOR-swizzled: slot (row, cp) holds global chunk cp ^ (row&7)
// (16B chunks, 8 per 128B row) -> fragment reads spread across all bank quads
// (2 lanes/bank = free), instead of 16 lanes on one quad (row stride 128B = 32 banks).
#define BM 128
#define BN 128
#define BK 64

__global__ __launch_bounds__(256) void gemm_bt_k(
    const unsigned short* __restrict__ A, const unsigned short* __restrict__ B,
    float* __restrict__ C, int M, int N, int K) {
  __shared__ __align__(16) unsigned short sA[BM * BK];
  __shared__ __align__(16) unsigned short sB[BN * BK];
  const int tid  = threadIdx.x;
  const int lane = tid & 63;
  const int wave = tid >> 6;
  const int bm = blockIdx.y * BM;
  const int bn = blockIdx.x * BN;
  const int wm = (wave >> 1) * 64;
  const int wn = (wave & 1) * 64;

  f32x4 acc[4][4];
#pragma unroll
  for (int i = 0; i < 4; ++i)
#pragma unroll
    for (int j = 0; j < 4; ++j) acc[i][j] = (f32x4){0.f, 0.f, 0.f, 0.f};

  const int srow = lane >> 3;                     // 0..7 within 8-row chunk
  const int scol = ((lane & 7) ^ srow) * 8;       // XOR-swizzled source chunk
  const int fr = lane & 15;
  const int fq = lane >> 4;

  for (int k0 = 0; k0 < K; k0 += BK) {
    // stage A,B tiles: chunk c covers rows [c*8, c*8+8), 64 lanes x 16B = 1KB
#pragma unroll
    for (int i = 0; i < 4; ++i) {
      const int c = wave * 4 + i;
      const int row = c * 8 + srow;
      __builtin_amdgcn_global_load_lds(
          (AS1 unsigned int*)(A + (size_t)(bm + row) * K + k0 + scol),
          (AS3 unsigned int*)(sA + c * 512), 16, 0, 0);
      __builtin_amdgcn_global_load_lds(
          (AS1 unsigned int*)(B + (size_t)(bn + row) * K + k0 + scol),
          (AS3 unsigned int*)(sB + c * 512), 16, 0, 0);
    }
    __syncthreads();
#pragma unroll
    for (int ks = 0; ks < 2; ++ks) {
      bf16x8 af[4], bfr[4];
#pragma unroll
      for (int mi = 0; mi < 4; ++mi) {
        const int row = wm + mi * 16 + fr;
        af[mi] = *(const bf16x8*)(sA + row * BK + (((ks * 4 + fq) ^ (fr & 7)) * 8));
      }
#pragma unroll
      for (int ni = 0; ni < 4; ++ni) {
        const int row = wn + ni * 16 + fr;
        bfr[ni] = *(const bf16x8*)(sB + row * BK + (((ks * 4 + fq) ^ (fr & 7)) * 8));
      }
#pragma unroll
      for (int mi = 0; mi < 4; ++mi)
#pragma unroll
        for (int ni = 0; ni < 4; ++ni)
          acc[mi][ni] = __builtin_amdgcn_mfma_f32_16x16x32_bf16(af[mi], bfr[ni], acc[mi][ni], 0, 0, 0);
    }
    __syncthreads();
  }

  // C/D layout: col = lane&15, row = (lane>>4)*4 + reg
#pragma unroll
  for (int mi = 0; mi < 4; ++mi) {
#pragma unroll
    for (int ni = 0; ni < 4; ++ni) {
      const int row0 = bm + wm + mi * 16 + fq * 4;
      const int col  = bn + wn + ni * 16 + fr;
#pragma unroll
      for (int r = 0; r < 4; ++r)
        C[(size_t)(row0 + r) * N + col] = acc[mi][ni][r];
    }
  }
}

// Safety-net exact fp32 kernel (only if ws_size too small) — slow but correct.
__global__ void naive_k(const float* __restrict__ x, const float* __restrict__ signs,
                        const float* __restrict__ ps, const float* __restrict__ rt,
                        float* __restrict__ out, int M, int N, int K, int P) {
  int idx = blockIdx.x * blockDim.x + threadIdx.x;
  if (idx >= M * N) return;
  int m = idx / N, n = idx % N;
  const float* xr = x + (size_t)m * K;
  const float* wr = signs + (size_t)n * K;
  const int NG = K / 128;
  const size_t G = (size_t)N * NG;
  float acc = 0.f;
  for (int g = 0; g < NG; ++g) {
    float sc = 0.f;
    int gi = n * NG + g;
    for (int p = 0; p < P; ++p) sc += rt[p] * ps[(size_t)p * G + gi];
    float s2 = 0.f;
    for (int kk = 0; kk < 128; ++kk) s2 += xr[g * 128 + kk] * wr[g * 128 + kk];
    acc += sc * s2;
  }
  out[idx] = acc;
}

extern "C" void kernel_launch(void* const* d_in, const int* in_sizes, int n_in,
                              void* d_out, int out_size, void* d_ws, size_t ws_size,
                              hipStream_t stream) {
  const float* x     = (const float*)d_in[0];
  const float* signs = (const float*)d_in[1];
  const float* ps    = (const float*)d_in[2];
  const float* rt    = (const float*)d_in[3];
  float* out = (float*)d_out;

  const int K = 4096, N = 4096, GS = 128;
  const int M = in_sizes[0] / K;   // 8192
  const int G = N / GS * K;        // 131072 groups (contiguous in flat [N*K])
  const int P = in_sizes[3];       // 8

  const size_t xb_bytes = (size_t)M * K * 2;
  const size_t wb_bytes = (size_t)N * K * 2;
  const size_t bl_bytes = (size_t)G * 4;
  const size_t need = xb_bytes + wb_bytes + bl_bytes;

  if (ws_size >= need) {
    unsigned short* xb = (unsigned short*)d_ws;
    unsigned short* wb = (unsigned short*)((char*)d_ws + xb_bytes);
    float* blended     = (float*)((char*)d_ws + xb_bytes + wb_bytes);

    blend_k<<<(G + 255) / 256, 256, 0, stream>>>(ps, rt, blended, G, P);

    const int n8w = N * K / 8;
    build_w_k<<<(n8w + 255) / 256, 256, 0, stream>>>(
        (const float4*)signs, blended, (ushort4*)wb, n8w);

    const int n8x = M * K / 8;
    cvt_x_k<<<(n8x + 255) / 256, 256, 0, stream>>>(
        (const float4*)x, (ushort4*)xb, n8x);

    dim3 grid(N / BN, M / BM);
    gemm_bt_k<<<grid, 256, 0, stream>>>(xb, wb, out, M, N, K);
  } else {
    const size_t total = (size_t)M * N;
    naive_k<<<(int)((total + 255) / 256), 256, 0, stream>>>(
        x, signs, ps, rt, out, M, N, K, P);
  }
}

// Round 3
// 437.514 us; speedup vs baseline: 1.5134x; 1.3661x over previous
//
#include <hip/hip_runtime.h>
#include <stdint.h>

#define AS1 __attribute__((address_space(1)))
#define AS3 __attribute__((address_space(3)))

typedef __attribute__((ext_vector_type(4))) int i32x4;

// ---------------- blend: blended[g] = sum_p routing[p] * ps[p*G+g] ----------
__global__ void blend_k(const float* __restrict__ ps, const float* __restrict__ rt,
                        float* __restrict__ blended, int G, int P) {
  int g = blockIdx.x * blockDim.x + threadIdx.x;
  if (g >= G) return;
  float s = 0.f;
  for (int p = 0; p < P; ++p) s += rt[p] * ps[(size_t)p * G + g];
  blended[g] = s;
}

__device__ __forceinline__ int q8(float v, float s) {
  int q = (int)rintf(v * s);
  q = q > 127 ? 127 : q;
  q = q < -127 ? -127 : q;
  return q & 0xff;
}

// ---------------- quantize W: w_q[i] = sign(signs[i]) * round(127*blended[i/128])
// 16 elems/thread, contiguous; 16B int4 store.
__global__ void quant_w_k(const float4* __restrict__ signs, const float* __restrict__ blended,
                          int4* __restrict__ wq, int n16) {
  int t = blockIdx.x * blockDim.x + threadIdx.x;
  if (t >= n16) return;
  float bl = blended[t >> 3];             // (t*16) >> 7
  int q = (int)rintf(bl * 127.f);
  q = q > 127 ? 127 : q; q = q < 1 ? 1 : q;
  int b[16];
#pragma unroll
  for (int i = 0; i < 4; ++i) {
    float4 s = signs[t * 4 + i];
    b[i * 4 + 0] = (s.x >= 0.f ? q : -q) & 0xff;
    b[i * 4 + 1] = (s.y >= 0.f ? q : -q) & 0xff;
    b[i * 4 + 2] = (s.z >= 0.f ? q : -q) & 0xff;
    b[i * 4 + 3] = (s.w >= 0.f ? q : -q) & 0xff;
  }
  int4 o;
  o.x = b[0] | (b[1] << 8) | (b[2] << 16) | (b[3] << 24);
  o.y = b[4] | (b[5] << 8) | (b[6] << 16) | (b[7] << 24);
  o.z = b[8] | (b[9] << 8) | (b[10] << 16) | (b[11] << 24);
  o.w = b[12] | (b[13] << 8) | (b[14] << 16) | (b[15] << 24);
  wq[t] = o;
}

// ---------------- quantize X per row: one block per row (K=4096, 256 thr) ----
// x_q = round(x * 127/rowmax); rowinv[m] = rowmax/(127*127)
__global__ __launch_bounds__(256) void quant_x_k(const float4* __restrict__ x,
                                                 int* __restrict__ xq,
                                                 float* __restrict__ rowinv, int K) {
  const int m = blockIdx.x;
  const int t = threadIdx.x;
  const int lane = t & 63;
  const int wave = t >> 6;
  const float4* xr = x + (size_t)m * (K / 4);
  float4 v[4];
  float amax = 0.f;
#pragma unroll
  for (int i = 0; i < 4; ++i) {
    v[i] = xr[t + 256 * i];
    amax = fmaxf(amax, fmaxf(fmaxf(fabsf(v[i].x), fabsf(v[i].y)),
                             fmaxf(fabsf(v[i].z), fabsf(v[i].w))));
  }
#pragma unroll
  for (int off = 1; off < 64; off <<= 1)
    amax = fmaxf(amax, __shfl_xor(amax, off));
  __shared__ float red[4];
  if (lane == 0) red[wave] = amax;
  __syncthreads();
  amax = fmaxf(fmaxf(red[0], red[1]), fmaxf(red[2], red[3]));
  const float s = 127.f / amax;
  if (t == 0) rowinv[m] = amax / (127.f * 127.f);
  int* xo = xq + (size_t)m * (K / 4);
#pragma unroll
  for (int i = 0; i < 4; ++i) {
    int p = q8(v[i].x, s) | (q8(v[i].y, s) << 8) | (q8(v[i].z, s) << 16) | (q8(v[i].w, s) << 24);
    xo[t + 256 * i] = p;
  }
}

// ---------------- i8 GEMM: C[M,N] = (A[M,K] * B[N,K]^T) * rowinv[m] ---------
// 128x128 tile, BK=128 i8 (128B/row), 4 waves 2x2, each 64x64 via 4x4 of
// mfma_i32_16x16x64_i8. XOR-swizzled LDS (chunk cp holds global chunk cp^(row&7)).
#define BM 128
#define BN 128
#define BKB 128

__global__ __launch_bounds__(256) void gemm_i8_k(
    const signed char* __restrict__ A, const signed char* __restrict__ B,
    const float* __restrict__ rowinv, float* __restrict__ C, int M, int N, int K) {
  __shared__ __align__(16) signed char sA[BM * BKB];
  __shared__ __align__(16) signed char sB[BN * BKB];
  const int tid  = threadIdx.x;
  const int lane = tid & 63;
  const int wave = tid >> 6;
  const int bm = blockIdx.y * BM;
  const int bn = blockIdx.x * BN;
  const int wm = (wave >> 1) * 64;
  const int wn = (wave & 1) * 64;

  i32x4 acc[4][4];
#pragma unroll
  for (int i = 0; i < 4; ++i)
#pragma unroll
    for (int j = 0; j < 4; ++j) acc[i][j] = (i32x4){0, 0, 0, 0};

  const int srow = lane >> 3;                    // 0..7 within 8-row chunk
  const int scol = ((lane & 7) ^ srow) * 16;     // XOR-swizzled source byte offset
  const int fr = lane & 15;
  const int fq = lane >> 4;

  for (int k0 = 0; k0 < K; k0 += BKB) {
    // stage: tile is 128 rows x 128B = 16 chunks of 1KB; 4 A + 4 B chunks/wave
#pragma unroll
    for (int i = 0; i < 4; ++i) {
      const int c = wave * 4 + i;
      const int row = c * 8 + srow;
      __builtin_amdgcn_global_load_lds(
          (AS1 unsigned int*)(A + (size_t)(bm + row) * K + k0 + scol),
          (AS3 unsigned int*)(sA + c * 1024), 16, 0, 0);
      __builtin_amdgcn_global_load_lds(
          (AS1 unsigned int*)(B + (size_t)(bn + row) * K + k0 + scol),
          (AS3 unsigned int*)(sB + c * 1024), 16, 0, 0);
    }
    __syncthreads();
#pragma unroll
    for (int ks = 0; ks < 2; ++ks) {
      i32x4 af[4], bf[4];
#pragma unroll
      for (int mi = 0; mi < 4; ++mi) {
        const int row = wm + mi * 16 + fr;
        af[mi] = *(const i32x4*)(sA + row * BKB + (((ks * 4 + fq) ^ (fr & 7)) * 16));
      }
#pragma unroll
      for (int ni = 0; ni < 4; ++ni) {
        const int row = wn + ni * 16 + fr;
        bf[ni] = *(const i32x4*)(sB + row * BKB + (((ks * 4 + fq) ^ (fr & 7)) * 16));
      }
#pragma unroll
      for (int mi = 0; mi < 4; ++mi)
#pragma unroll
        for (int ni = 0; ni < 4; ++ni)
          acc[mi][ni] = __builtin_amdgcn_mfma_i32_16x16x64_i8(af[mi], bf[ni], acc[mi][ni], 0, 0, 0);
    }
    __syncthreads();
  }

  // C/D layout: col = lane&15, row = (lane>>4)*4 + reg
#pragma unroll
  for (int mi = 0; mi < 4; ++mi) {
    const int row0 = bm + wm + mi * 16 + fq * 4;
    float ri[4];
#pragma unroll
    for (int r = 0; r < 4; ++r) ri[r] = rowinv[row0 + r];
#pragma unroll
    for (int ni = 0; ni < 4; ++ni) {
      const int col = bn + wn + ni * 16 + fr;
#pragma unroll
      for (int r = 0; r < 4; ++r)
        C[(size_t)(row0 + r) * N + col] = (float)acc[mi][ni][r] * ri[r];
    }
  }
}

// Safety-net exact fp32 kernel (only if ws_size too small) — slow but correct.
__global__ void naive_k(const float* __restrict__ x, const float* __restrict__ signs,
                        const float* __restrict__ ps, const float* __restrict__ rt,
                        float* __restrict__ out, int M, int N, int K, int P) {
  int idx = blockIdx.x * blockDim.x + threadIdx.x;
  if (idx >= M * N) return;
  int m = idx / N, n = idx % N;
  const float* xr = x + (size_t)m * K;
  const float* wr = signs + (size_t)n * K;
  const int NG = K / 128;
  const size_t G = (size_t)N * NG;
  float acc = 0.f;
  for (int g = 0; g < NG; ++g) {
    float sc = 0.f;
    int gi = n * NG + g;
    for (int p = 0; p < P; ++p) sc += rt[p] * ps[(size_t)p * G + gi];
    float s2 = 0.f;
    for (int kk = 0; kk < 128; ++kk) s2 += xr[g * 128 + kk] * wr[g * 128 + kk];
    acc += sc * s2;
  }
  out[idx] = acc;
}

extern "C" void kernel_launch(void* const* d_in, const int* in_sizes, int n_in,
                              void* d_out, int out_size, void* d_ws, size_t ws_size,
                              hipStream_t stream) {
  const float* x     = (const float*)d_in[0];
  const float* signs = (const float*)d_in[1];
  const float* ps    = (const float*)d_in[2];
  const float* rt    = (const float*)d_in[3];
  float* out = (float*)d_out;

  const int K = 4096, N = 4096, GS = 128;
  const int M = in_sizes[0] / K;   // 8192
  const int G = N / GS * K;        // 131072 flat groups over [N*K]
  const int P = in_sizes[3];       // 8

  const size_t xq_bytes = (size_t)M * K;       // 33.5 MB
  const size_t wq_bytes = (size_t)N * K;       // 16.8 MB
  const size_t bl_bytes = (size_t)G * 4;       // 0.5 MB
  const size_t ri_bytes = (size_t)M * 4;       // 32 KB
  const size_t need = xq_bytes + wq_bytes + bl_bytes + ri_bytes;

  if (ws_size >= need) {
    signed char* xq = (signed char*)d_ws;
    signed char* wq = (signed char*)((char*)d_ws + xq_bytes);
    float* blended  = (float*)((char*)d_ws + xq_bytes + wq_bytes);
    float* rowinv   = (float*)((char*)d_ws + xq_bytes + wq_bytes + bl_bytes);

    blend_k<<<(G + 255) / 256, 256, 0, stream>>>(ps, rt, blended, G, P);

    const int n16w = N * K / 16;
    quant_w_k<<<(n16w + 255) / 256, 256, 0, stream>>>(
        (const float4*)signs, blended, (int4*)wq, n16w);

    quant_x_k<<<M, 256, 0, stream>>>((const float4*)x, (int*)xq, rowinv, K);

    dim3 grid(N / BN, M / BM);
    gemm_i8_k<<<grid, 256, 0, stream>>>(xq, wq, rowinv, out, M, N, K);
  } else {
    const size_t total = (size_t)M * N;
    naive_k<<<(int)((total + 255) / 256), 256, 0, stream>>>(
        x, signs, ps, rt, out, M, N, K, P);
  }
}

// Round 4
// 425.247 us; speedup vs baseline: 1.5571x; 1.0288x over previous
//
#include <hip/hip_runtime.h>
#include <stdint.h>

#define AS1 __attribute__((address_space(1)))
#define AS3 __attribute__((address_space(3)))

typedef __attribute__((ext_vector_type(4))) int i32x4;
typedef __attribute__((ext_vector_type(16))) int i32x16;

// ---------------- blend: blended[g] = sum_p routing[p] * ps[p*G+g] ----------
__global__ void blend_k(const float* __restrict__ ps, const float* __restrict__ rt,
                        float* __restrict__ blended, int G, int P) {
  int g = blockIdx.x * blockDim.x + threadIdx.x;
  if (g >= G) return;
  float s = 0.f;
  for (int p = 0; p < P; ++p) s += rt[p] * ps[(size_t)p * G + g];
  blended[g] = s;
}

__device__ __forceinline__ int q8(float v, float s) {
  int q = (int)rintf(v * s);
  q = q > 127 ? 127 : q;
  q = q < -127 ? -127 : q;
  return q & 0xff;
}

// ---------------- quantize W: w_q[i] = sign(signs[i]) * round(127*blended[i/128])
// 16 elems/thread, contiguous; 16B int4 store.
__global__ void quant_w_k(const float4* __restrict__ signs, const float* __restrict__ blended,
                          int4* __restrict__ wq, int n16) {
  int t = blockIdx.x * blockDim.x + threadIdx.x;
  if (t >= n16) return;
  float bl = blended[t >> 3];             // (t*16) >> 7
  int q = (int)rintf(bl * 127.f);
  q = q > 127 ? 127 : q; q = q < 1 ? 1 : q;
  int b[16];
#pragma unroll
  for (int i = 0; i < 4; ++i) {
    float4 s = signs[t * 4 + i];
    b[i * 4 + 0] = (s.x >= 0.f ? q : -q) & 0xff;
    b[i * 4 + 1] = (s.y >= 0.f ? q : -q) & 0xff;
    b[i * 4 + 2] = (s.z >= 0.f ? q : -q) & 0xff;
    b[i * 4 + 3] = (s.w >= 0.f ? q : -q) & 0xff;
  }
  int4 o;
  o.x = b[0] | (b[1] << 8) | (b[2] << 16) | (b[3] << 24);
  o.y = b[4] | (b[5] << 8) | (b[6] << 16) | (b[7] << 24);
  o.z = b[8] | (b[9] << 8) | (b[10] << 16) | (b[11] << 24);
  o.w = b[12] | (b[13] << 8) | (b[14] << 16) | (b[15] << 24);
  wq[t] = o;
}

// ---------------- quantize X per row: one block per row (K=4096, 256 thr) ----
// x_q = round(x * 127/rowmax); rowinv[m] = rowmax/(127*127)
__global__ __launch_bounds__(256) void quant_x_k(const float4* __restrict__ x,
                                                 int* __restrict__ xq,
                                                 float* __restrict__ rowinv, int K) {
  const int m = blockIdx.x;
  const int t = threadIdx.x;
  const int lane = t & 63;
  const int wave = t >> 6;
  const float4* xr = x + (size_t)m * (K / 4);
  float4 v[4];
  float amax = 0.f;
#pragma unroll
  for (int i = 0; i < 4; ++i) {
    v[i] = xr[t + 256 * i];
    amax = fmaxf(amax, fmaxf(fmaxf(fabsf(v[i].x), fabsf(v[i].y)),
                             fmaxf(fabsf(v[i].z), fabsf(v[i].w))));
  }
#pragma unroll
  for (int off = 1; off < 64; off <<= 1)
    amax = fmaxf(amax, __shfl_xor(amax, off));
  __shared__ float red[4];
  if (lane == 0) red[wave] = amax;
  __syncthreads();
  amax = fmaxf(fmaxf(red[0], red[1]), fmaxf(red[2], red[3]));
  const float s = 127.f / amax;
  if (t == 0) rowinv[m] = amax / (127.f * 127.f);
  int* xo = xq + (size_t)m * (K / 4);
#pragma unroll
  for (int i = 0; i < 4; ++i) {
    int p = q8(v[i].x, s) | (q8(v[i].y, s) << 8) | (q8(v[i].z, s) << 16) | (q8(v[i].w, s) << 24);
    xo[t + 256 * i] = p;
  }
}

// ---------------- i8 GEMM: C[M,N] = (A[M,K] * B[N,K]^T) * rowinv[m] ---------
// 128x128 tile, BK=128 i8 (128B/row), 4 waves 2x2, each wave 64x64 via 2x2 of
// mfma_i32_32x32x32_i8 (half the MFMA issue slots of the 16x16x64 variant,
// 12% higher shape ceiling: 4404 vs 3944 TOPS ubench).
// XOR-swizzled LDS: slot (row, cp) holds global 16B chunk cp ^ (row&7).
#define BM 128
#define BN 128
#define BKB 128

__global__ __launch_bounds__(256) void gemm_i8_k(
    const signed char* __restrict__ A, const signed char* __restrict__ B,
    const float* __restrict__ rowinv, float* __restrict__ C, int M, int N, int K) {
  __shared__ __align__(16) signed char sA[BM * BKB];
  __shared__ __align__(16) signed char sB[BN * BKB];
  const int tid  = threadIdx.x;
  const int lane = tid & 63;
  const int wave = tid >> 6;
  const int bm = blockIdx.y * BM;
  const int bn = blockIdx.x * BN;
  const int wm = (wave >> 1) * 64;
  const int wn = (wave & 1) * 64;

  i32x16 acc[2][2];
#pragma unroll
  for (int i = 0; i < 2; ++i)
#pragma unroll
    for (int j = 0; j < 2; ++j)
#pragma unroll
      for (int r = 0; r < 16; ++r) acc[i][j][r] = 0;

  const int srow = lane >> 3;                    // 0..7 within 8-row chunk
  const int scol = ((lane & 7) ^ srow) * 16;     // XOR-swizzled source byte offset
  const int fl = lane & 31;                      // fragment row (A) / col (B)
  const int fh = lane >> 5;                      // K half selector

  for (int k0 = 0; k0 < K; k0 += BKB) {
    // stage: tile is 128 rows x 128B = 16 chunks of 1KB; 4 A + 4 B chunks/wave
#pragma unroll
    for (int i = 0; i < 4; ++i) {
      const int c = wave * 4 + i;
      const int row = c * 8 + srow;
      __builtin_amdgcn_global_load_lds(
          (AS1 unsigned int*)(A + (size_t)(bm + row) * K + k0 + scol),
          (AS3 unsigned int*)(sA + c * 1024), 16, 0, 0);
      __builtin_amdgcn_global_load_lds(
          (AS1 unsigned int*)(B + (size_t)(bn + row) * K + k0 + scol),
          (AS3 unsigned int*)(sB + c * 1024), 16, 0, 0);
    }
    __syncthreads();
    // A-frag (32x32x32 i8): m = lane&31, k = (lane>>5)*16 + j, 16B/lane.
    // Per ks2 (32 i8 of K): chunk c = ks2*2 + fh, stored at c ^ (row&7).
#pragma unroll
    for (int ks2 = 0; ks2 < 4; ++ks2) {
      i32x4 af[2], bf[2];
#pragma unroll
      for (int mi = 0; mi < 2; ++mi) {
        const int row = wm + mi * 32 + fl;
        af[mi] = *(const i32x4*)(sA + row * BKB + (((ks2 * 2 + fh) ^ (row & 7)) * 16));
      }
#pragma unroll
      for (int ni = 0; ni < 2; ++ni) {
        const int row = wn + ni * 32 + fl;
        bf[ni] = *(const i32x4*)(sB + row * BKB + (((ks2 * 2 + fh) ^ (row & 7)) * 16));
      }
#pragma unroll
      for (int mi = 0; mi < 2; ++mi)
#pragma unroll
        for (int ni = 0; ni < 2; ++ni)
          acc[mi][ni] = __builtin_amdgcn_mfma_i32_32x32x32_i8(af[mi], bf[ni], acc[mi][ni], 0, 0, 0);
    }
    __syncthreads();
  }

  // C/D layout (32x32): col = lane&31, row = (reg&3) + 8*(reg>>2) + 4*(lane>>5)
#pragma unroll
  for (int mi = 0; mi < 2; ++mi) {
    const int rbase = bm + wm + mi * 32 + 4 * fh;
    float ri[16];
#pragma unroll
    for (int r = 0; r < 16; ++r) ri[r] = rowinv[rbase + (r & 3) + 8 * (r >> 2)];
#pragma unroll
    for (int ni = 0; ni < 2; ++ni) {
      const int col = bn + wn + ni * 32 + fl;
#pragma unroll
      for (int r = 0; r < 16; ++r) {
        const int row = rbase + (r & 3) + 8 * (r >> 2);
        C[(size_t)row * N + col] = (float)acc[mi][ni][r] * ri[r];
      }
    }
  }
}

// Safety-net exact fp32 kernel (only if ws_size too small) — slow but correct.
__global__ void naive_k(const float* __restrict__ x, const float* __restrict__ signs,
                        const float* __restrict__ ps, const float* __restrict__ rt,
                        float* __restrict__ out, int M, int N, int K, int P) {
  int idx = blockIdx.x * blockDim.x + threadIdx.x;
  if (idx >= M * N) return;
  int m = idx / N, n = idx % N;
  const float* xr = x + (size_t)m * K;
  const float* wr = signs + (size_t)n * K;
  const int NG = K / 128;
  const size_t G = (size_t)N * NG;
  float acc = 0.f;
  for (int g = 0; g < NG; ++g) {
    float sc = 0.f;
    int gi = n * NG + g;
    for (int p = 0; p < P; ++p) sc += rt[p] * ps[(size_t)p * G + gi];
    float s2 = 0.f;
    for (int kk = 0; kk < 128; ++kk) s2 += xr[g * 128 + kk] * wr[g * 128 + kk];
    acc += sc * s2;
  }
  out[idx] = acc;
}

extern "C" void kernel_launch(void* const* d_in, const int* in_sizes, int n_in,
                              void* d_out, int out_size, void* d_ws, size_t ws_size,
                              hipStream_t stream) {
  const float* x     = (const float*)d_in[0];
  const float* signs = (const float*)d_in[1];
  const float* ps    = (const float*)d_in[2];
  const float* rt    = (const float*)d_in[3];
  float* out = (float*)d_out;

  const int K = 4096, N = 4096, GS = 128;
  const int M = in_sizes[0] / K;   // 8192
  const int G = N / GS * K;        // 131072 flat groups over [N*K]
  const int P = in_sizes[3];       // 8

  const size_t xq_bytes = (size_t)M * K;       // 33.5 MB
  const size_t wq_bytes = (size_t)N * K;       // 16.8 MB
  const size_t bl_bytes = (size_t)G * 4;       // 0.5 MB
  const size_t ri_bytes = (size_t)M * 4;       // 32 KB
  const size_t need = xq_bytes + wq_bytes + bl_bytes + ri_bytes;

  if (ws_size >= need) {
    signed char* xq = (signed char*)d_ws;
    signed char* wq = (signed char*)((char*)d_ws + xq_bytes);
    float* blended  = (float*)((char*)d_ws + xq_bytes + wq_bytes);
    float* rowinv   = (float*)((char*)d_ws + xq_bytes + wq_bytes + bl_bytes);

    blend_k<<<(G + 255) / 256, 256, 0, stream>>>(ps, rt, blended, G, P);

    const int n16w = N * K / 16;
    quant_w_k<<<(n16w + 255) / 256, 256, 0, stream>>>(
        (const float4*)signs, blended, (int4*)wq, n16w);

    quant_x_k<<<M, 256, 0, stream>>>((const float4*)x, (int*)xq, rowinv, K);

    dim3 grid(N / BN, M / BM);
    gemm_i8_k<<<grid, 256, 0, stream>>>(xq, wq, rowinv, out, M, N, K);
  } else {
    const size_t total = (size_t)M * N;
    naive_k<<<(int)((total + 255) / 256), 256, 0, stream>>>(
        x, signs, ps, rt, out, M, N, K, P);
  }
}